// Round 3
// baseline (983.325 us; speedup 1.0000x reference)
//
#include <hip/hip_runtime.h>
#include <cstdint>

// ---------------------------------------------------------------------------
// Edge2NodeProp: e = (rbf @ W_rbf^T) * x ; h = segment_sum(e, idx_i);
//                h = swish(h@W1^T+b1) x3; out = h @ W_out^T
//
// R3: node MLP rewritten as register-tiled block GEMM.
//   Old node_kernel: 1 ds_read_b32 + 1 readlane + 1 FMA per MAC (~480us).
//   New node_gemm: block=256 thr=64 nodes, thread computes 4x4 tile;
//   per k4: 4 float4 LDS(H) + 4 float4 global(W, L1-hot) -> 64 FMA.
//   LDS H ping-pong [64][68] padded (2-way bank aliasing = free).
// Edge phase (CSR build + gather) unchanged from R2 (verified).
// ---------------------------------------------------------------------------

// ---------------- CSR build ----------------

__global__ __launch_bounds__(256) void k_hist(
    const int* __restrict__ idx, int* __restrict__ counts, int n_edges)
{
    const int i = blockIdx.x * blockDim.x + threadIdx.x;
    const int stride = gridDim.x * blockDim.x;
    for (int e = i; e < n_edges; e += stride)
        atomicAdd(&counts[idx[e]], 1);
}

__global__ __launch_bounds__(256) void k_scan1(
    const int* __restrict__ counts, int* __restrict__ offsets,
    int* __restrict__ blocksum, int n_nodes)
{
    __shared__ int sh[256];
    const int t = threadIdx.x;
    const int i = blockIdx.x * 256 + t;
    const int v = (i < n_nodes) ? counts[i] : 0;
    sh[t] = v;
    __syncthreads();
    for (int off = 1; off < 256; off <<= 1) {
        const int add = (t >= off) ? sh[t - off] : 0;
        __syncthreads();
        sh[t] += add;
        __syncthreads();
    }
    if (i < n_nodes) offsets[i] = sh[t] - v;   // exclusive, block-local
    if (t == 255) blocksum[blockIdx.x] = sh[255];
}

__global__ __launch_bounds__(512) void k_scan2(int* __restrict__ blocksum, int nb)
{
    __shared__ int sh[512];
    const int t = threadIdx.x;
    const int v = (t < nb) ? blocksum[t] : 0;
    sh[t] = v;
    __syncthreads();
    for (int off = 1; off < 512; off <<= 1) {
        const int add = (t >= off) ? sh[t - off] : 0;
        __syncthreads();
        sh[t] += add;
        __syncthreads();
    }
    if (t < nb) blocksum[t] = sh[t] - v;       // exclusive block base
}

__global__ __launch_bounds__(256) void k_addbase(
    int* __restrict__ offsets, const int* __restrict__ blocksum,
    int* __restrict__ cursor, int n_nodes, int n_edges)
{
    const int i = blockIdx.x * 256 + threadIdx.x;
    if (i < n_nodes) {
        const int o = offsets[i] + blocksum[blockIdx.x];
        offsets[i] = o;
        cursor[i]  = o;
    }
    if (i == 0) offsets[n_nodes] = n_edges;
}

__global__ __launch_bounds__(256) void k_scatter(
    const int* __restrict__ idx, int* __restrict__ cursor,
    int* __restrict__ perm, int n_edges)
{
    const int i = blockIdx.x * blockDim.x + threadIdx.x;
    const int stride = gridDim.x * blockDim.x;
    for (int e = i; e < n_edges; e += stride) {
        const int pos = atomicAdd(&cursor[idx[e]], 1);
        perm[pos] = e;
    }
}

// ---------------- gather: one wave per node, lane = dim (unchanged) --------
__global__ __launch_bounds__(256) void k_gather(
    const float* __restrict__ x,       // (E,64)
    const float* __restrict__ rbf,     // (E,16)
    const int*   __restrict__ offsets, // (N+1)
    const int*   __restrict__ perm,    // (E)
    const float* __restrict__ Wrbf,    // (64,16)
    float* __restrict__ hacc,          // (N,64)
    int n_nodes)
{
    const int lane = threadIdx.x & 63;
    const int n    = blockIdx.x * (blockDim.x >> 6) + (threadIdx.x >> 6);
    if (n >= n_nodes) return;

    float w[16];
    {
        const float4* wp = (const float4*)(Wrbf + (size_t)lane * 16);
        float4 a = wp[0], b = wp[1], c = wp[2], d = wp[3];
        w[0]=a.x; w[1]=a.y; w[2]=a.z; w[3]=a.w;
        w[4]=b.x; w[5]=b.y; w[6]=b.z; w[7]=b.w;
        w[8]=c.x; w[9]=c.y; w[10]=c.z; w[11]=c.w;
        w[12]=d.x; w[13]=d.y; w[14]=d.z; w[15]=d.w;
    }

    const int s     = offsets[n];
    const int e_end = offsets[n + 1];

    float acc = 0.0f;
    int e = (s < e_end) ? perm[s] : 0;
    for (int j = s; j < e_end; ++j) {
        const int e_nxt = (j + 1 < e_end) ? perm[j + 1] : 0;

        const float4* rp = (const float4*)(rbf + (size_t)e * 16);
        float4 r0 = rp[0], r1 = rp[1], r2 = rp[2], r3 = rp[3];
        const float xv = x[(size_t)e * 64 + lane];

        float g = 0.0f;
        g = fmaf(r0.x, w[0],  g); g = fmaf(r0.y, w[1],  g);
        g = fmaf(r0.z, w[2],  g); g = fmaf(r0.w, w[3],  g);
        g = fmaf(r1.x, w[4],  g); g = fmaf(r1.y, w[5],  g);
        g = fmaf(r1.z, w[6],  g); g = fmaf(r1.w, w[7],  g);
        g = fmaf(r2.x, w[8],  g); g = fmaf(r2.y, w[9],  g);
        g = fmaf(r2.z, w[10], g); g = fmaf(r2.w, w[11], g);
        g = fmaf(r3.x, w[12], g); g = fmaf(r3.y, w[13], g);
        g = fmaf(r3.z, w[14], g); g = fmaf(r3.w, w[15], g);

        acc = fmaf(g, xv, acc);
        e = e_nxt;
    }
    hacc[(size_t)n * 64 + lane] = acc;
}

// ---------------- fallback atomic scatter (used only if ws too small) ------
__global__ __launch_bounds__(256) void edge_kernel(
    const float* __restrict__ x, const float* __restrict__ rbf,
    const int* __restrict__ idx, const float* __restrict__ Wrbf,
    float* __restrict__ hacc, int n_edges, int n_nodes)
{
    const int lane   = threadIdx.x & 63;
    const int wave   = blockIdx.x * (blockDim.x >> 6) + (threadIdx.x >> 6);
    const int nwaves = gridDim.x * (blockDim.x >> 6);

    float w[16];
    {
        const float4* wp = (const float4*)(Wrbf + (size_t)lane * 16);
        float4 a = wp[0], b = wp[1], c = wp[2], d = wp[3];
        w[0]=a.x; w[1]=a.y; w[2]=a.z; w[3]=a.w;
        w[4]=b.x; w[5]=b.y; w[6]=b.z; w[7]=b.w;
        w[8]=c.x; w[9]=c.y; w[10]=c.z; w[11]=c.w;
        w[12]=d.x; w[13]=d.y; w[14]=d.z; w[15]=d.w;
    }

    for (int e = wave; e < n_edges; e += nwaves) {
        const int node = idx[e];
        const float4* rp = (const float4*)(rbf + (size_t)e * 16);
        float4 r0 = rp[0], r1 = rp[1], r2 = rp[2], r3 = rp[3];
        float rv[16] = { r0.x, r0.y, r0.z, r0.w, r1.x, r1.y, r1.z, r1.w,
                         r2.x, r2.y, r2.z, r2.w, r3.x, r3.y, r3.z, r3.w };
        float g = 0.0f;
#pragma unroll
        for (int r = 0; r < 16; ++r) g = fmaf(rv[r], w[r], g);
        const float xv = x[(size_t)e * 64 + lane];
        if ((unsigned)node < (unsigned)n_nodes)
            atomicAdd(&hacc[(size_t)node * 64 + lane], g * xv);
    }
}

// ---------------------------------------------------------------------------
// Phase 2: node MLP as register-tiled block GEMM.
//   Block: 256 threads / 4 waves, 64 nodes. Thread (tn,td) computes the
//   4x4 tile nodes [4tn..4tn+3] x dims [4td..4td+3].
//   H in LDS [64][68] (pad 4 -> 2-way bank aliasing, free). W from global
//   (16KB/layer, L1-hot). Layer3 fused with wo-dot + 16-lane reduce.
// ---------------------------------------------------------------------------
__device__ __forceinline__ void gemm_tile(
    const float (*__restrict__ Hin)[68], const float* __restrict__ Wg,
    int n0, int d0, float acc[4][4])
{
#pragma unroll
    for (int i = 0; i < 4; ++i)
#pragma unroll
        for (int j = 0; j < 4; ++j) acc[i][j] = 0.0f;

#pragma unroll 2
    for (int k4 = 0; k4 < 16; ++k4) {
        float4 h4[4], w4[4];
#pragma unroll
        for (int i = 0; i < 4; ++i)
            h4[i] = *(const float4*)(&Hin[n0 + i][k4 * 4]);
#pragma unroll
        for (int j = 0; j < 4; ++j)
            w4[j] = *(const float4*)(Wg + (size_t)(d0 + j) * 64 + k4 * 4);
#pragma unroll
        for (int i = 0; i < 4; ++i)
#pragma unroll
            for (int j = 0; j < 4; ++j) {
                acc[i][j] = fmaf(h4[i].x, w4[j].x, acc[i][j]);
                acc[i][j] = fmaf(h4[i].y, w4[j].y, acc[i][j]);
                acc[i][j] = fmaf(h4[i].z, w4[j].z, acc[i][j]);
                acc[i][j] = fmaf(h4[i].w, w4[j].w, acc[i][j]);
            }
    }
}

__device__ __forceinline__ float swish_f(float v)
{
    return v / (1.0f + __expf(-v));
}

__global__ __launch_bounds__(256) void node_gemm(
    const float* __restrict__ hacc,
    const float* __restrict__ W1, const float* __restrict__ b1,
    const float* __restrict__ W2, const float* __restrict__ b2,
    const float* __restrict__ W3, const float* __restrict__ b3,
    const float* __restrict__ Wout,
    float* __restrict__ out, int n_nodes)
{
    __shared__ float Ha[64][68];
    __shared__ float Hb[64][68];
    __shared__ float bsh[3][64];
    __shared__ float wosh[64];

    const int t    = threadIdx.x;
    const int base = blockIdx.x * 64;

    if (t < 64) {
        bsh[0][t] = b1[t];
        bsh[1][t] = b2[t];
        bsh[2][t] = b3[t];
        wosh[t]   = Wout[t];
    }

    // Load 64x64 hacc tile -> Ha (coalesced global, conflict-free LDS write).
    {
        const int tc = t & 15;     // col quad
        const int r0 = t >> 4;     // 0..15
#pragma unroll
        for (int rr = 0; rr < 4; ++rr) {
            const int r    = r0 + rr * 16;
            const int node = base + r;
            float4 v = make_float4(0.f, 0.f, 0.f, 0.f);
            if (node < n_nodes)
                v = *(const float4*)(hacc + (size_t)node * 64 + tc * 4);
            *(float4*)(&Ha[r][tc * 4]) = v;
        }
    }
    __syncthreads();

    const int lane = t & 63;
    const int w    = t >> 6;
    const int td   = lane & 15;
    const int tn   = (lane >> 4) + (w << 2);
    const int d0   = td * 4;
    const int n0   = tn * 4;

    float acc[4][4];

    // Layer 1: Ha -> Hb
    gemm_tile(Ha, W1, n0, d0, acc);
#pragma unroll
    for (int i = 0; i < 4; ++i) {
        float4 o;
        o.x = swish_f(acc[i][0] + bsh[0][d0 + 0]);
        o.y = swish_f(acc[i][1] + bsh[0][d0 + 1]);
        o.z = swish_f(acc[i][2] + bsh[0][d0 + 2]);
        o.w = swish_f(acc[i][3] + bsh[0][d0 + 3]);
        *(float4*)(&Hb[n0 + i][d0]) = o;
    }
    __syncthreads();

    // Layer 2: Hb -> Ha
    gemm_tile(Hb, W2, n0, d0, acc);
#pragma unroll
    for (int i = 0; i < 4; ++i) {
        float4 o;
        o.x = swish_f(acc[i][0] + bsh[1][d0 + 0]);
        o.y = swish_f(acc[i][1] + bsh[1][d0 + 1]);
        o.z = swish_f(acc[i][2] + bsh[1][d0 + 2]);
        o.w = swish_f(acc[i][3] + bsh[1][d0 + 3]);
        *(float4*)(&Ha[n0 + i][d0]) = o;
    }
    __syncthreads();

    // Layer 3 fused with out-dot: Ha -> p[i] = sum_d swish(.)*wo[d]
    gemm_tile(Ha, W3, n0, d0, acc);
    float p[4];
#pragma unroll
    for (int i = 0; i < 4; ++i) {
        float s = 0.0f;
        s = fmaf(swish_f(acc[i][0] + bsh[2][d0 + 0]), wosh[d0 + 0], s);
        s = fmaf(swish_f(acc[i][1] + bsh[2][d0 + 1]), wosh[d0 + 1], s);
        s = fmaf(swish_f(acc[i][2] + bsh[2][d0 + 2]), wosh[d0 + 2], s);
        s = fmaf(swish_f(acc[i][3] + bsh[2][d0 + 3]), wosh[d0 + 3], s);
        p[i] = s;
    }
    // Reduce across the 16 lanes (td=0..15) of this tn group.
#pragma unroll
    for (int i = 0; i < 4; ++i) {
        p[i] += __shfl_xor(p[i], 8, 64);
        p[i] += __shfl_xor(p[i], 4, 64);
        p[i] += __shfl_xor(p[i], 2, 64);
        p[i] += __shfl_xor(p[i], 1, 64);
    }
    if (td == 0) {
#pragma unroll
        for (int i = 0; i < 4; ++i) {
            const int node = base + n0 + i;
            if (node < n_nodes) out[node] = p[i];
        }
    }
}

// ---------------------------------------------------------------------------
extern "C" void kernel_launch(void* const* d_in, const int* in_sizes, int n_in,
                              void* d_out, int out_size, void* d_ws, size_t ws_size,
                              hipStream_t stream)
{
    const float* x    = (const float*)d_in[0];
    const float* rbf  = (const float*)d_in[1];
    const int*   idx  = (const int*)d_in[2];
    const float* Wrbf = (const float*)d_in[4];
    const float* W1   = (const float*)d_in[5];
    const float* b1   = (const float*)d_in[6];
    const float* W2   = (const float*)d_in[7];
    const float* b2   = (const float*)d_in[8];
    const float* W3   = (const float*)d_in[9];
    const float* b3   = (const float*)d_in[10];
    const float* Wout = (const float*)d_in[11];

    const int n_edges = in_sizes[0] / 64;
    const int n_nodes = out_size;   // OUT_DIM == 1

    const size_t N_pad = ((size_t)n_nodes + 1 + 63) & ~(size_t)63;
    const size_t E_pad = ((size_t)n_edges + 63) & ~(size_t)63;
    int*   counts = (int*)d_ws;              // N  (reused as cursor)
    int*   offs   = counts + N_pad;          // N+1
    int*   bsum   = offs + N_pad;            // <=512
    int*   perm   = bsum + 512;              // E
    float* hacc   = (float*)(perm + E_pad);  // N*64 f32

    const size_t need = (2 * N_pad + 512 + E_pad) * sizeof(int)
                      + (size_t)n_nodes * 64 * sizeof(float);

    const int NB = (n_nodes + 255) / 256;    // 391 for N=100K (<=512)

    if (ws_size >= need && NB <= 512) {
        hipMemsetAsync(counts, 0, (size_t)n_nodes * sizeof(int), stream);
        k_hist   <<<2048, 256, 0, stream>>>(idx, counts, n_edges);
        k_scan1  <<<NB,   256, 0, stream>>>(counts, offs, bsum, n_nodes);
        k_scan2  <<<1,    512, 0, stream>>>(bsum, NB);
        k_addbase<<<NB,   256, 0, stream>>>(offs, bsum, counts, n_nodes, n_edges);
        k_scatter<<<2048, 256, 0, stream>>>(idx, counts, perm, n_edges);

        const int gblocks = (n_nodes + 3) / 4;
        k_gather<<<gblocks, 256, 0, stream>>>(x, rbf, offs, perm, Wrbf,
                                              hacc, n_nodes);
    } else {
        hacc = (float*)d_ws;
        hipMemsetAsync(hacc, 0, (size_t)n_nodes * 64 * sizeof(float), stream);
        edge_kernel<<<8192, 256, 0, stream>>>(x, rbf, idx, Wrbf, hacc,
                                              n_edges, n_nodes);
    }

    const int mlp_blocks = (n_nodes + 63) / 64;
    node_gemm<<<mlp_blocks, 256, 0, stream>>>(hacc, W1, b1, W2, b2, W3, b3,
                                              Wout, (float*)d_out, n_nodes);
}

// Round 4
// 848.730 us; speedup vs baseline: 1.1586x; 1.1586x over previous
//
#include <hip/hip_runtime.h>
#include <cstdint>

// ---------------------------------------------------------------------------
// Edge2NodeProp: e = (rbf @ W_rbf^T) * x ; h = segment_sum(e, idx_i);
//                h = swish(h@W1^T+b1) x3; out = h @ W_out^T
//
// R4: k_gather rewritten as latency-pipelined quad-gather.
//   Old: serial perm->x chain per wave (~1 edge in flight) -> 885 GB/s, 304us.
//   New: reassociated reduction M[r] = sum_e rbf[e][r]*x[e][lane], finish
//        h = W*M once per node. Main loop: 4 edges/iter, ids in SGPR
//        (readfirstlane), 4 independent x loads in flight, next-quad id
//        prefetch. CSR build + node_gemm unchanged (attribution).
// ---------------------------------------------------------------------------

// ---------------- CSR build ----------------

__global__ __launch_bounds__(256) void k_hist(
    const int* __restrict__ idx, int* __restrict__ counts, int n_edges)
{
    const int i = blockIdx.x * blockDim.x + threadIdx.x;
    const int stride = gridDim.x * blockDim.x;
    for (int e = i; e < n_edges; e += stride)
        atomicAdd(&counts[idx[e]], 1);
}

__global__ __launch_bounds__(256) void k_scan1(
    const int* __restrict__ counts, int* __restrict__ offsets,
    int* __restrict__ blocksum, int n_nodes)
{
    __shared__ int sh[256];
    const int t = threadIdx.x;
    const int i = blockIdx.x * 256 + t;
    const int v = (i < n_nodes) ? counts[i] : 0;
    sh[t] = v;
    __syncthreads();
    for (int off = 1; off < 256; off <<= 1) {
        const int add = (t >= off) ? sh[t - off] : 0;
        __syncthreads();
        sh[t] += add;
        __syncthreads();
    }
    if (i < n_nodes) offsets[i] = sh[t] - v;   // exclusive, block-local
    if (t == 255) blocksum[blockIdx.x] = sh[255];
}

__global__ __launch_bounds__(512) void k_scan2(int* __restrict__ blocksum, int nb)
{
    __shared__ int sh[512];
    const int t = threadIdx.x;
    const int v = (t < nb) ? blocksum[t] : 0;
    sh[t] = v;
    __syncthreads();
    for (int off = 1; off < 512; off <<= 1) {
        const int add = (t >= off) ? sh[t - off] : 0;
        __syncthreads();
        sh[t] += add;
        __syncthreads();
    }
    if (t < nb) blocksum[t] = sh[t] - v;       // exclusive block base
}

__global__ __launch_bounds__(256) void k_addbase(
    int* __restrict__ offsets, const int* __restrict__ blocksum,
    int* __restrict__ cursor, int n_nodes, int n_edges)
{
    const int i = blockIdx.x * 256 + threadIdx.x;
    if (i < n_nodes) {
        const int o = offsets[i] + blocksum[blockIdx.x];
        offsets[i] = o;
        cursor[i]  = o;
    }
    if (i == 0) offsets[n_nodes] = n_edges;
}

__global__ __launch_bounds__(256) void k_scatter(
    const int* __restrict__ idx, int* __restrict__ cursor,
    int* __restrict__ perm, int n_edges)
{
    const int i = blockIdx.x * blockDim.x + threadIdx.x;
    const int stride = gridDim.x * blockDim.x;
    for (int e = i; e < n_edges; e += stride) {
        const int pos = atomicAdd(&cursor[idx[e]], 1);
        perm[pos] = e;
    }
}

// ---------------- gather: one wave per node, lane = dim --------------------
// M[r] += rbf[e][r] * x[e][lane]  (outer-product accumulate, 16 VGPR)
// h[lane] = sum_r W[lane][r] * M[r]  (once per node)
// Main loop: quads of 4 edges, SGPR ids, 4 x-loads in flight.
// ---------------------------------------------------------------------------
__device__ __forceinline__ void rbf_accum(
    const float* __restrict__ rbf, int e, float xv, float M[16])
{
    const float4* rp = (const float4*)(rbf + (size_t)e * 16);
    float4 r0 = rp[0], r1 = rp[1], r2 = rp[2], r3 = rp[3];
    M[0]  = fmaf(r0.x, xv, M[0]);  M[1]  = fmaf(r0.y, xv, M[1]);
    M[2]  = fmaf(r0.z, xv, M[2]);  M[3]  = fmaf(r0.w, xv, M[3]);
    M[4]  = fmaf(r1.x, xv, M[4]);  M[5]  = fmaf(r1.y, xv, M[5]);
    M[6]  = fmaf(r1.z, xv, M[6]);  M[7]  = fmaf(r1.w, xv, M[7]);
    M[8]  = fmaf(r2.x, xv, M[8]);  M[9]  = fmaf(r2.y, xv, M[9]);
    M[10] = fmaf(r2.z, xv, M[10]); M[11] = fmaf(r2.w, xv, M[11]);
    M[12] = fmaf(r3.x, xv, M[12]); M[13] = fmaf(r3.y, xv, M[13]);
    M[14] = fmaf(r3.z, xv, M[14]); M[15] = fmaf(r3.w, xv, M[15]);
}

__global__ __launch_bounds__(256) void k_gather(
    const float* __restrict__ x,       // (E,64)
    const float* __restrict__ rbf,     // (E,16)
    const int*   __restrict__ offsets, // (N+1)
    const int*   __restrict__ perm,    // (E)
    const float* __restrict__ Wrbf,    // (64,16)
    float* __restrict__ hacc,          // (N,64)
    int n_nodes)
{
    const int lane = threadIdx.x & 63;
    int n = blockIdx.x * (blockDim.x >> 6) + (threadIdx.x >> 6);
    n = __builtin_amdgcn_readfirstlane(n);
    if (n >= n_nodes) return;

    // Per-lane W_rbf row (16 f32 = 64B contiguous).
    float w[16];
    {
        const float4* wp = (const float4*)(Wrbf + (size_t)lane * 16);
        float4 a = wp[0], b = wp[1], c = wp[2], d = wp[3];
        w[0]=a.x; w[1]=a.y; w[2]=a.z; w[3]=a.w;
        w[4]=b.x; w[5]=b.y; w[6]=b.z; w[7]=b.w;
        w[8]=c.x; w[9]=c.y; w[10]=c.z; w[11]=c.w;
        w[12]=d.x; w[13]=d.y; w[14]=d.z; w[15]=d.w;
    }

    const int s     = __builtin_amdgcn_readfirstlane(offsets[n]);
    const int e_end = __builtin_amdgcn_readfirstlane(offsets[n + 1]);

    float M[16];
#pragma unroll
    for (int r = 0; r < 16; ++r) M[r] = 0.0f;

    int j = s;
    const int cnt = e_end - s;

    // Remainder first (0..3 edges) so the main loop is exact quads.
    const int rem = cnt & 3;
    for (int k = 0; k < rem; ++k, ++j) {
        const int e = __builtin_amdgcn_readfirstlane(perm[j]);
        const float xv = x[(size_t)e * 64 + lane];
        rbf_accum(rbf, e, xv, M);
    }

    // Main loop: quads with next-quad id prefetch.
    if (j < e_end) {
        int e0 = __builtin_amdgcn_readfirstlane(perm[j + 0]);
        int e1 = __builtin_amdgcn_readfirstlane(perm[j + 1]);
        int e2 = __builtin_amdgcn_readfirstlane(perm[j + 2]);
        int e3 = __builtin_amdgcn_readfirstlane(perm[j + 3]);
        while (j < e_end) {
            // 4 independent random 256B streams, issued back-to-back.
            const float xv0 = x[(size_t)e0 * 64 + lane];
            const float xv1 = x[(size_t)e1 * 64 + lane];
            const float xv2 = x[(size_t)e2 * 64 + lane];
            const float xv3 = x[(size_t)e3 * 64 + lane];
            const int c0 = e0, c1 = e1, c2 = e2, c3 = e3;

            j += 4;
            if (j < e_end) {   // prefetch next quad ids (range is exact quads)
                e0 = __builtin_amdgcn_readfirstlane(perm[j + 0]);
                e1 = __builtin_amdgcn_readfirstlane(perm[j + 1]);
                e2 = __builtin_amdgcn_readfirstlane(perm[j + 2]);
                e3 = __builtin_amdgcn_readfirstlane(perm[j + 3]);
            }

            rbf_accum(rbf, c0, xv0, M);
            rbf_accum(rbf, c1, xv1, M);
            rbf_accum(rbf, c2, xv2, M);
            rbf_accum(rbf, c3, xv3, M);
        }
    }

    // Finish: h[lane] = sum_r W[lane][r] * M[r]
    float acc = 0.0f;
#pragma unroll
    for (int r = 0; r < 16; ++r) acc = fmaf(w[r], M[r], acc);
    hacc[(size_t)n * 64 + lane] = acc;
}

// ---------------- fallback atomic scatter (used only if ws too small) ------
__global__ __launch_bounds__(256) void edge_kernel(
    const float* __restrict__ x, const float* __restrict__ rbf,
    const int* __restrict__ idx, const float* __restrict__ Wrbf,
    float* __restrict__ hacc, int n_edges, int n_nodes)
{
    const int lane   = threadIdx.x & 63;
    const int wave   = blockIdx.x * (blockDim.x >> 6) + (threadIdx.x >> 6);
    const int nwaves = gridDim.x * (blockDim.x >> 6);

    float w[16];
    {
        const float4* wp = (const float4*)(Wrbf + (size_t)lane * 16);
        float4 a = wp[0], b = wp[1], c = wp[2], d = wp[3];
        w[0]=a.x; w[1]=a.y; w[2]=a.z; w[3]=a.w;
        w[4]=b.x; w[5]=b.y; w[6]=b.z; w[7]=b.w;
        w[8]=c.x; w[9]=c.y; w[10]=c.z; w[11]=c.w;
        w[12]=d.x; w[13]=d.y; w[14]=d.z; w[15]=d.w;
    }

    for (int e = wave; e < n_edges; e += nwaves) {
        const int node = idx[e];
        const float4* rp = (const float4*)(rbf + (size_t)e * 16);
        float4 r0 = rp[0], r1 = rp[1], r2 = rp[2], r3 = rp[3];
        float rv[16] = { r0.x, r0.y, r0.z, r0.w, r1.x, r1.y, r1.z, r1.w,
                         r2.x, r2.y, r2.z, r2.w, r3.x, r3.y, r3.z, r3.w };
        float g = 0.0f;
#pragma unroll
        for (int r = 0; r < 16; ++r) g = fmaf(rv[r], w[r], g);
        const float xv = x[(size_t)e * 64 + lane];
        if ((unsigned)node < (unsigned)n_nodes)
            atomicAdd(&hacc[(size_t)node * 64 + lane], g * xv);
    }
}

// ---------------------------------------------------------------------------
// Phase 2: node MLP as register-tiled block GEMM (unchanged from R3).
// ---------------------------------------------------------------------------
__device__ __forceinline__ void gemm_tile(
    const float (*__restrict__ Hin)[68], const float* __restrict__ Wg,
    int n0, int d0, float acc[4][4])
{
#pragma unroll
    for (int i = 0; i < 4; ++i)
#pragma unroll
        for (int j = 0; j < 4; ++j) acc[i][j] = 0.0f;

#pragma unroll 2
    for (int k4 = 0; k4 < 16; ++k4) {
        float4 h4[4], w4[4];
#pragma unroll
        for (int i = 0; i < 4; ++i)
            h4[i] = *(const float4*)(&Hin[n0 + i][k4 * 4]);
#pragma unroll
        for (int j = 0; j < 4; ++j)
            w4[j] = *(const float4*)(Wg + (size_t)(d0 + j) * 64 + k4 * 4);
#pragma unroll
        for (int i = 0; i < 4; ++i)
#pragma unroll
            for (int j = 0; j < 4; ++j) {
                acc[i][j] = fmaf(h4[i].x, w4[j].x, acc[i][j]);
                acc[i][j] = fmaf(h4[i].y, w4[j].y, acc[i][j]);
                acc[i][j] = fmaf(h4[i].z, w4[j].z, acc[i][j]);
                acc[i][j] = fmaf(h4[i].w, w4[j].w, acc[i][j]);
            }
    }
}

__device__ __forceinline__ float swish_f(float v)
{
    return v / (1.0f + __expf(-v));
}

__global__ __launch_bounds__(256) void node_gemm(
    const float* __restrict__ hacc,
    const float* __restrict__ W1, const float* __restrict__ b1,
    const float* __restrict__ W2, const float* __restrict__ b2,
    const float* __restrict__ W3, const float* __restrict__ b3,
    const float* __restrict__ Wout,
    float* __restrict__ out, int n_nodes)
{
    __shared__ float Ha[64][68];
    __shared__ float Hb[64][68];
    __shared__ float bsh[3][64];
    __shared__ float wosh[64];

    const int t    = threadIdx.x;
    const int base = blockIdx.x * 64;

    if (t < 64) {
        bsh[0][t] = b1[t];
        bsh[1][t] = b2[t];
        bsh[2][t] = b3[t];
        wosh[t]   = Wout[t];
    }

    {
        const int tc = t & 15;
        const int r0 = t >> 4;
#pragma unroll
        for (int rr = 0; rr < 4; ++rr) {
            const int r    = r0 + rr * 16;
            const int node = base + r;
            float4 v = make_float4(0.f, 0.f, 0.f, 0.f);
            if (node < n_nodes)
                v = *(const float4*)(hacc + (size_t)node * 64 + tc * 4);
            *(float4*)(&Ha[r][tc * 4]) = v;
        }
    }
    __syncthreads();

    const int lane = t & 63;
    const int w    = t >> 6;
    const int td   = lane & 15;
    const int tn   = (lane >> 4) + (w << 2);
    const int d0   = td * 4;
    const int n0   = tn * 4;

    float acc[4][4];

    gemm_tile(Ha, W1, n0, d0, acc);
#pragma unroll
    for (int i = 0; i < 4; ++i) {
        float4 o;
        o.x = swish_f(acc[i][0] + bsh[0][d0 + 0]);
        o.y = swish_f(acc[i][1] + bsh[0][d0 + 1]);
        o.z = swish_f(acc[i][2] + bsh[0][d0 + 2]);
        o.w = swish_f(acc[i][3] + bsh[0][d0 + 3]);
        *(float4*)(&Hb[n0 + i][d0]) = o;
    }
    __syncthreads();

    gemm_tile(Hb, W2, n0, d0, acc);
#pragma unroll
    for (int i = 0; i < 4; ++i) {
        float4 o;
        o.x = swish_f(acc[i][0] + bsh[1][d0 + 0]);
        o.y = swish_f(acc[i][1] + bsh[1][d0 + 1]);
        o.z = swish_f(acc[i][2] + bsh[1][d0 + 2]);
        o.w = swish_f(acc[i][3] + bsh[1][d0 + 3]);
        *(float4*)(&Ha[n0 + i][d0]) = o;
    }
    __syncthreads();

    gemm_tile(Ha, W3, n0, d0, acc);
    float p[4];
#pragma unroll
    for (int i = 0; i < 4; ++i) {
        float s = 0.0f;
        s = fmaf(swish_f(acc[i][0] + bsh[2][d0 + 0]), wosh[d0 + 0], s);
        s = fmaf(swish_f(acc[i][1] + bsh[2][d0 + 1]), wosh[d0 + 1], s);
        s = fmaf(swish_f(acc[i][2] + bsh[2][d0 + 2]), wosh[d0 + 2], s);
        s = fmaf(swish_f(acc[i][3] + bsh[2][d0 + 3]), wosh[d0 + 3], s);
        p[i] = s;
    }
#pragma unroll
    for (int i = 0; i < 4; ++i) {
        p[i] += __shfl_xor(p[i], 8, 64);
        p[i] += __shfl_xor(p[i], 4, 64);
        p[i] += __shfl_xor(p[i], 2, 64);
        p[i] += __shfl_xor(p[i], 1, 64);
    }
    if (td == 0) {
#pragma unroll
        for (int i = 0; i < 4; ++i) {
            const int node = base + n0 + i;
            if (node < n_nodes) out[node] = p[i];
        }
    }
}

// ---------------------------------------------------------------------------
extern "C" void kernel_launch(void* const* d_in, const int* in_sizes, int n_in,
                              void* d_out, int out_size, void* d_ws, size_t ws_size,
                              hipStream_t stream)
{
    const float* x    = (const float*)d_in[0];
    const float* rbf  = (const float*)d_in[1];
    const int*   idx  = (const int*)d_in[2];
    const float* Wrbf = (const float*)d_in[4];
    const float* W1   = (const float*)d_in[5];
    const float* b1   = (const float*)d_in[6];
    const float* W2   = (const float*)d_in[7];
    const float* b2   = (const float*)d_in[8];
    const float* W3   = (const float*)d_in[9];
    const float* b3   = (const float*)d_in[10];
    const float* Wout = (const float*)d_in[11];

    const int n_edges = in_sizes[0] / 64;
    const int n_nodes = out_size;   // OUT_DIM == 1

    const size_t N_pad = ((size_t)n_nodes + 1 + 63) & ~(size_t)63;
    const size_t E_pad = ((size_t)n_edges + 63) & ~(size_t)63;
    int*   counts = (int*)d_ws;              // N  (reused as cursor)
    int*   offs   = counts + N_pad;          // N+1
    int*   bsum   = offs + N_pad;            // <=512
    int*   perm   = bsum + 512;              // E
    float* hacc   = (float*)(perm + E_pad);  // N*64 f32

    const size_t need = (2 * N_pad + 512 + E_pad) * sizeof(int)
                      + (size_t)n_nodes * 64 * sizeof(float);

    const int NB = (n_nodes + 255) / 256;    // 391 for N=100K (<=512)

    if (ws_size >= need && NB <= 512) {
        hipMemsetAsync(counts, 0, (size_t)n_nodes * sizeof(int), stream);
        k_hist   <<<2048, 256, 0, stream>>>(idx, counts, n_edges);
        k_scan1  <<<NB,   256, 0, stream>>>(counts, offs, bsum, n_nodes);
        k_scan2  <<<1,    512, 0, stream>>>(bsum, NB);
        k_addbase<<<NB,   256, 0, stream>>>(offs, bsum, counts, n_nodes, n_edges);
        k_scatter<<<2048, 256, 0, stream>>>(idx, counts, perm, n_edges);

        const int gblocks = (n_nodes + 3) / 4;
        k_gather<<<gblocks, 256, 0, stream>>>(x, rbf, offs, perm, Wrbf,
                                              hacc, n_nodes);
    } else {
        hacc = (float*)d_ws;
        hipMemsetAsync(hacc, 0, (size_t)n_nodes * 64 * sizeof(float), stream);
        edge_kernel<<<8192, 256, 0, stream>>>(x, rbf, idx, Wrbf, hacc,
                                              n_edges, n_nodes);
    }

    const int mlp_blocks = (n_nodes + 63) / 64;
    node_gemm<<<mlp_blocks, 256, 0, stream>>>(hacc, W1, b1, W2, b2, W3, b3,
                                              Wout, (float*)d_out, n_nodes);
}